// Round 11
// baseline (25.129 us; speedup 1.0000x reference)
//
#include <hip/hip_runtime.h>

// Problem constants (from reference setup_inputs)
#define B_  4
#define H_  64
#define W_  64
#define C_  16
#define F_  32

#define NWE (8 * 9 * F_)   // 2304 float4 weight entries = 36864 B
#define NXE (3 * 34 * 4)   // 408 float4 x-stage chunks   =  6528 B

// Round-11 = round-10 kernel with ONE change: __launch_bounds__(512, 4).
// Rationale: compute-phase VGPR demand ~130-150; without an occupancy floor
// hipcc may allocate >128 VGPRs -> only 3 waves/SIMD fit -> a 512-thr block
// (2 waves/SIMD) can only be resident ONCE per CU (8 waves/CU) -> latency
// exposed (observed ~45% effective VALU util). Floor=4 waves/EU pins
// VGPR<=128 -> 2 blocks/CU = 16 waves/CU. Demand is near the cap so this
// should NOT spill (r8's disaster was demand ~300 vs cap 128).
// Spill signature to check: FETCH/WRITE >> 10 MB.
__global__ __launch_bounds__(512, 4) void mtp_main(const float* __restrict__ x,
                                                   const float* __restrict__ kern,
                                                   const float* __restrict__ tker,
                                                   float* __restrict__ out) {
    __shared__ float4 wlds[NWE];                 // [ccp(8)][q(9)][f(32)] = (t0,t1,k0,k1)
    __shared__ float2 xlds[3][34][8];            // [row][padded col][channel pair]

    const int tid  = threadIdx.x;
    const int bidx = blockIdx.x;                 // (b*64 + i)*2 + half
    const int half = bidx & 1;
    const int i    = (bidx >> 1) & 63;
    const int b    = bidx >> 7;

    // ---- stage weights (coalesced: consecutive tid = consecutive f) ----
    for (int e = tid; e < NWE; e += 512) {
        int f   = e & 31;
        int t   = e >> 5;
        int q   = t % 9;
        int ccp = t / 9;
        int s0 = (q * C_ + ccp * 2 + 0) * F_ + f;
        int s1 = (q * C_ + ccp * 2 + 1) * F_ + f;
        wlds[e] = make_float4(tker[s0], tker[s1], kern[s0], kern[s1]);
    }
    // ---- stage x halo (zero-padded): rows i-1..i+1, cols half*32-1 .. +32 ----
    for (int e = tid; e < NXE; e += 512) {
        int cc4 = e & 3;
        int t   = e >> 2;
        int cl  = t % 34;                        // local padded col
        int di  = t / 34;
        int ro  = i + di - 1;
        int co  = half * 32 + cl - 1;
        float4 v = make_float4(0.f, 0.f, 0.f, 0.f);
        if (ro >= 0 && ro < H_ && co >= 0 && co < W_)
            v = *reinterpret_cast<const float4*>(
                    x + ((b * H_ + ro) * W_ + co) * C_ + cc4 * 4);
        *reinterpret_cast<float4*>(&xlds[di][cl][cc4 * 2]) = v;
    }
    __syncthreads();

    const int lane = tid & 63;
    const int f    = lane & 31;
    const int g    = lane >> 5;                  // channel-group half
    const int w    = tid >> 6;                   // wave 0..7
    const int w4   = w << 2;                     // strip base (padded-local col)

    float acc[4][4];                             // [px][r] partial over 8 channels
    #pragma unroll
    for (int px = 0; px < 4; ++px)
        #pragma unroll
        for (int r = 0; r < 4; ++r) acc[px][r] = 0.f;

    const int wbase = g * (4 * 9 * F_) + f;      // float4-entry index base

    #pragma unroll 1
    for (int it = 0; it < 4; ++it) {             // 4 channel-pairs of this half
        const int pidx = g * 4 + it;             // this lane's channel pair

        // weights: 9 ds_read_b128; halves read different ccp
        float4 wq[9];
        #pragma unroll
        for (int q = 0; q < 9; ++q)
            wq[q] = wlds[wbase + (it * 9 + q) * F_];

        // x halo from LDS: 3 rows x 6 cols float2 (2 distinct addrs/wave each)
        float2 xh[3][6];
        #pragma unroll
        for (int dr = 0; dr < 3; ++dr)
            #pragma unroll
            for (int lc = 0; lc < 6; ++lc)
                xh[dr][lc] = xlds[dr][w4 + lc][pidx];

        #pragma unroll
        for (int px = 0; px < 4; ++px) {
            #pragma unroll
            for (int r = 0; r < 4; ++r) {
                float z0[9], z1[9];
                #pragma unroll
                for (int q = 0; q < 9; ++q) {
                    const int a = q / 3, bq = q % 3;
                    int di, dj;
                    switch (r) {   // x position = rot_r^{-1}(weight position q)
                        case 0:  di = a;      dj = bq;     break;
                        case 1:  di = 2 - bq; dj = a;      break;
                        case 2:  di = 2 - a;  dj = 2 - bq; break;
                        default: di = bq;     dj = 2 - a;  break;
                    }
                    const float2 xv = xh[di][px + dj];
                    z0[q] = fmaf(xv.x, wq[q].x, wq[q].z);
                    z1[q] = fmaf(xv.y, wq[q].y, wq[q].w);
                }
                float m0 = fmaxf(fmaxf(fmaxf(z0[0], z0[1]), z0[2]),
                           fmaxf(fmaxf(fmaxf(z0[3], z0[4]), z0[5]),
                                 fmaxf(fmaxf(z0[6], z0[7]), z0[8])));
                float m1 = fmaxf(fmaxf(fmaxf(z1[0], z1[1]), z1[2]),
                           fmaxf(fmaxf(fmaxf(z1[3], z1[4]), z1[5]),
                                 fmaxf(fmaxf(z1[6], z1[7]), z1[8])));
                acc[px][r] += m0 + m1;
            }
        }
    }

    // ---- cross-half reduce: total = (ch 0-7 partial) + (ch 8-15 partial)
    float tot[4][4];
    #pragma unroll
    for (int px = 0; px < 4; ++px)
        #pragma unroll
        for (int r = 0; r < 4; ++r)
            tot[px][r] = acc[px][r] + __shfl_xor(acc[px][r], 32, 64);

    // ---- store: per (r,slot) lane writes px = slot*2 + g -> 256B contiguous.
    const int jg = half * 32 + w4 + g;
    #pragma unroll
    for (int r = 0; r < 4; ++r) {
        float* op = out + ((((b * 4 + r) * H_ + i) * W_ + jg) * F_ + f);
        float v0 = g ? tot[1][r] : tot[0][r];
        float v1 = g ? tot[3][r] : tot[2][r];
        op[0]      = v0;
        op[2 * F_] = v1;
    }
}

extern "C" void kernel_launch(void* const* d_in, const int* in_sizes, int n_in,
                              void* d_out, int out_size, void* d_ws, size_t ws_size,
                              hipStream_t stream) {
    const float* x    = (const float*)d_in[0];
    const float* kern = (const float*)d_in[1];
    const float* tker = (const float*)d_in[2];
    float* out = (float*)d_out;

    hipLaunchKernelGGL(mtp_main, dim3(B_ * H_ * 2), dim3(512), 0, stream,
                       x, kern, tker, out);
}

// Round 12
// 19.485 us; speedup vs baseline: 1.2897x; 1.2897x over previous
//
#include <hip/hip_runtime.h>

// Problem constants (from reference setup_inputs)
#define B_  4
#define H_  64
#define W_  64
#define C_  16
#define F_  32

#define NWE (8 * 9 * F_)   // 2304 float4 weight entries = 36864 B
#define NXE (3 * 34 * 4)   // 408 float4 x-stage chunks  =  6528 B

// Round-12 = round-5 champion structure with ONE change: wave covers an
// 8-px strip (was 4) -> weight ds_read_b128 amortized over 2x pixels.
// Block = 256 thr = 4 waves = half-row (32 px); 512 blocks; all-LDS.
// Lane = (ps, f); lane computes px = it*2+ps, it=0..3, all 16 ch, all 4 rot.
// DS/CU model: 17.3k cyc (was 25.3k in r5) vs VALU 14.3k cyc/SIMD -> balanced.
// Registers ~124 (wq 36 + xh 54 + acc 16 + temps) -> 4 waves/SIMD, no
// launch_bounds floor (r4/r8/r11 lesson: never cap the RA on this kernel).
// P4 via patch permutation (r3-r11 verified); cc-loop unroll 1 (r8 lesson).
__global__ __launch_bounds__(256) void mtp_main(const float* __restrict__ x,
                                                const float* __restrict__ kern,
                                                const float* __restrict__ tker,
                                                float* __restrict__ out) {
    __shared__ float4 wlds[NWE];                 // [ccp(8)][q(9)][f(32)] = (t0,t1,k0,k1)
    __shared__ float  xlds[3][34][16];           // [row][padded col][channel]

    const int tid  = threadIdx.x;
    const int bidx = blockIdx.x;                 // (b*64 + i)*2 + half
    const int half = bidx & 1;
    const int i    = (bidx >> 1) & 63;
    const int b    = bidx >> 7;

    // ---- stage weights: 2304 = 9 * 256 exactly; consecutive tid = consecutive f
    #pragma unroll
    for (int e0 = 0; e0 < 9; ++e0) {
        int e   = e0 * 256 + tid;
        int f   = e & 31;
        int t   = e >> 5;
        int q   = t % 9;
        int ccp = t / 9;
        int s0 = (q * C_ + ccp * 2 + 0) * F_ + f;
        int s1 = (q * C_ + ccp * 2 + 1) * F_ + f;
        wlds[e] = make_float4(tker[s0], tker[s1], kern[s0], kern[s1]);
    }
    // ---- stage x halo (zero-padded): rows i-1..i+1, cols half*32-1 .. +32 ----
    for (int e = tid; e < NXE; e += 256) {
        int cc4 = e & 3;
        int t   = e >> 2;
        int cl  = t % 34;                        // local padded col
        int di  = t / 34;
        int ro  = i + di - 1;
        int co  = half * 32 + cl - 1;
        float4 v = make_float4(0.f, 0.f, 0.f, 0.f);
        if (ro >= 0 && ro < H_ && co >= 0 && co < W_)
            v = *reinterpret_cast<const float4*>(
                    x + ((b * H_ + ro) * W_ + co) * C_ + cc4 * 4);
        *reinterpret_cast<float4*>(&xlds[di][cl][cc4 * 4]) = v;
    }
    __syncthreads();

    const int lane = tid & 63;
    const int f    = lane & 31;
    const int ps   = lane >> 5;
    const int w    = tid >> 6;                   // wave 0..3
    const int cb   = w * 8 + ps;                 // padded-col base for lc=0

    float acc[4][4];                             // [it][r]
    #pragma unroll
    for (int it = 0; it < 4; ++it)
        #pragma unroll
        for (int r = 0; r < 4; ++r) acc[it][r] = 0.f;

    #pragma unroll 1
    for (int cc = 0; cc < 8; ++cc) {
        // weights: 9 ds_read_b128 (ps halves broadcast-share)
        float4 wq[9];
        #pragma unroll
        for (int q = 0; q < 9; ++q)
            wq[q] = wlds[(cc * 9 + q) * F_ + f];

        // x halo: 3 rows x 9 cols float2 (2 distinct addrs/wave -> broadcast)
        float2 xh[3][9];
        #pragma unroll
        for (int dr = 0; dr < 3; ++dr)
            #pragma unroll
            for (int lc = 0; lc < 9; ++lc)
                xh[dr][lc] = *reinterpret_cast<const float2*>(&xlds[dr][cb + lc][cc * 2]);

        #pragma unroll
        for (int it = 0; it < 4; ++it) {
            #pragma unroll
            for (int r = 0; r < 4; ++r) {
                float z0[9], z1[9];
                #pragma unroll
                for (int q = 0; q < 9; ++q) {
                    const int a = q / 3, bq = q % 3;
                    int di, dj;
                    switch (r) {   // x position = rot_r^{-1}(weight position q)
                        case 0:  di = a;      dj = bq;     break;
                        case 1:  di = 2 - bq; dj = a;      break;
                        case 2:  di = 2 - a;  dj = 2 - bq; break;
                        default: di = bq;     dj = 2 - a;  break;
                    }
                    const float2 xv = xh[di][it * 2 + dj];
                    z0[q] = fmaf(xv.x, wq[q].x, wq[q].z);
                    z1[q] = fmaf(xv.y, wq[q].y, wq[q].w);
                }
                float m0 = fmaxf(fmaxf(fmaxf(z0[0], z0[1]), z0[2]),
                           fmaxf(fmaxf(fmaxf(z0[3], z0[4]), z0[5]),
                                 fmaxf(fmaxf(z0[6], z0[7]), z0[8])));
                float m1 = fmaxf(fmaxf(fmaxf(z1[0], z1[1]), z1[2]),
                           fmaxf(fmaxf(fmaxf(z1[3], z1[4]), z1[5]),
                                 fmaxf(fmaxf(z1[6], z1[7]), z1[8])));
                acc[it][r] += m0 + m1;
            }
        }
    }

    // ---- store: out[b, r, i, jg + it*2, f]; per (r,it) wave stores 256B
    const int jg = half * 32 + w * 8 + ps;
    #pragma unroll
    for (int r = 0; r < 4; ++r) {
        float* op = out + ((((b * 4 + r) * H_ + i) * W_ + jg) * F_ + f);
        #pragma unroll
        for (int it = 0; it < 4; ++it)
            op[it * 2 * F_] = acc[it][r];
    }
}

extern "C" void kernel_launch(void* const* d_in, const int* in_sizes, int n_in,
                              void* d_out, int out_size, void* d_ws, size_t ws_size,
                              hipStream_t stream) {
    const float* x    = (const float*)d_in[0];
    const float* kern = (const float*)d_in[1];
    const float* tker = (const float*)d_in[2];
    float* out = (float*)d_out;

    hipLaunchKernelGGL(mtp_main, dim3(B_ * H_ * 2), dim3(256), 0, stream,
                       x, kern, tker, out);
}

// Round 13
// 16.949 us; speedup vs baseline: 1.4826x; 1.1496x over previous
//
#include <hip/hip_runtime.h>

// Problem constants (from reference setup_inputs)
#define B_  4
#define H_  64
#define W_  64
#define C_  16
#define F_  32

#define NWE (8 * 9 * F_)   // 2304 weight entries; each = 2 h2 (wt, wk) = 8 B
#define NXE (3 * 34 * 4)   // 408 x-stage chunks (4 channels each)

typedef _Float16 h2 __attribute__((ext_vector_type(2)));

__device__ __forceinline__ h2 pack2(float a, float b) {
    h2 r; r.x = (_Float16)a; r.y = (_Float16)b; return r;
}

// acc += m.x + m.y (f32 accumulate of a packed f16 pair)
__device__ __forceinline__ float acc_dot2(h2 m, float c) {
#if __has_builtin(__builtin_amdgcn_fdot2)
    h2 one; one.x = (_Float16)1.0f; one.y = (_Float16)1.0f;
    return __builtin_amdgcn_fdot2(m, one, c, false);
#else
    return c + (float)m.x + (float)m.y;
#endif
}

// Round-13 = round-12 structure (all-LDS, 512 blocks x 256 thr, wave = 8-px
// strip, ps-split, P4 via patch permutation, cc-loop unroll 1) with ONE
// change: inner math in PACKED f16 (channel pairs -> v_pk_fma_f16 /
// v_pk_max_f16, f32 accumulate via v_dot2_f32_f16). VALU per (it,r):
// 28-36 f32 instr -> 18 packed instr (~1.6x cut); LDS 43.4 -> 21.7 KB.
// Numerics: |z|<=~9, f16 err ~0.01/z, sum over 16ch -> +~0.05-0.16 absmax
// (threshold 0.865, current 0.25 -> safe).
__global__ __launch_bounds__(256) void mtp_main(const float* __restrict__ x,
                                                const float* __restrict__ kern,
                                                const float* __restrict__ tker,
                                                float* __restrict__ out) {
    __shared__ h2 wlds[NWE * 2];        // [ccp(8)][q(9)][f(32)][{wt,wk}]  18432 B
    __shared__ h2 xlds[3][34][8];       // [row][padded col][ch pair]       3264 B

    const int tid  = threadIdx.x;
    const int bidx = blockIdx.x;        // (b*64 + i)*2 + half
    const int half = bidx & 1;
    const int i    = (bidx >> 1) & 63;
    const int b    = bidx >> 7;

    // ---- stage weights (f32 -> packed f16): consecutive tid = consecutive f
    #pragma unroll
    for (int e0 = 0; e0 < 9; ++e0) {
        int e   = e0 * 256 + tid;       // 2304 = 9*256 exactly
        int f   = e & 31;
        int t   = e >> 5;
        int q   = t % 9;
        int ccp = t / 9;
        int s0 = (q * C_ + ccp * 2 + 0) * F_ + f;
        int s1 = (q * C_ + ccp * 2 + 1) * F_ + f;
        wlds[e * 2 + 0] = pack2(tker[s0], tker[s1]);   // wt = times (slope)
        wlds[e * 2 + 1] = pack2(kern[s0], kern[s1]);   // wk = plus (offset)
    }
    // ---- stage x halo (zero-padded, f32 -> packed f16) ----
    for (int e = tid; e < NXE; e += 256) {
        int cc4 = e & 3;
        int t   = e >> 2;
        int cl  = t % 34;               // local padded col
        int di  = t / 34;
        int ro  = i + di - 1;
        int co  = half * 32 + cl - 1;
        float4 v = make_float4(0.f, 0.f, 0.f, 0.f);
        if (ro >= 0 && ro < H_ && co >= 0 && co < W_)
            v = *reinterpret_cast<const float4*>(
                    x + ((b * H_ + ro) * W_ + co) * C_ + cc4 * 4);
        xlds[di][cl][cc4 * 2 + 0] = pack2(v.x, v.y);
        xlds[di][cl][cc4 * 2 + 1] = pack2(v.z, v.w);
    }
    __syncthreads();

    const int lane = tid & 63;
    const int f    = lane & 31;
    const int ps   = lane >> 5;
    const int w    = tid >> 6;          // wave 0..3
    const int cb   = w * 8 + ps;        // padded-col base for lc=0

    float acc[4][4];                    // [it][r]
    #pragma unroll
    for (int it = 0; it < 4; ++it)
        #pragma unroll
        for (int r = 0; r < 4; ++r) acc[it][r] = 0.f;

    #pragma unroll 1
    for (int cc = 0; cc < 8; ++cc) {
        // weights: 9 x 8B (wt,wk adjacent -> merged ds_read)
        h2 wt[9], wk[9];
        #pragma unroll
        for (int q = 0; q < 9; ++q) {
            int bi = ((cc * 9 + q) * F_ + f) * 2;
            wt[q] = wlds[bi];
            wk[q] = wlds[bi + 1];
        }
        // x halo: 3 rows x 9 cols, 4B each (2 distinct addrs/wave -> broadcast)
        h2 xh[3][9];
        #pragma unroll
        for (int dr = 0; dr < 3; ++dr)
            #pragma unroll
            for (int lc = 0; lc < 9; ++lc)
                xh[dr][lc] = xlds[dr][cb + lc][cc];

        #pragma unroll
        for (int it = 0; it < 4; ++it) {
            #pragma unroll
            for (int r = 0; r < 4; ++r) {
                h2 z[9];
                #pragma unroll
                for (int q = 0; q < 9; ++q) {
                    const int a = q / 3, bq = q % 3;
                    int di, dj;
                    switch (r) {   // x position = rot_r^{-1}(weight position q)
                        case 0:  di = a;      dj = bq;     break;
                        case 1:  di = 2 - bq; dj = a;      break;
                        case 2:  di = 2 - a;  dj = 2 - bq; break;
                        default: di = bq;     dj = 2 - a;  break;
                    }
                    // v_pk_fma_f16 via fp-contract on packed mul+add
                    z[q] = xh[di][it * 2 + dj] * wt[q] + wk[q];
                }
                h2 m1 = __builtin_elementwise_max(__builtin_elementwise_max(z[0], z[1]), z[2]);
                h2 m2 = __builtin_elementwise_max(__builtin_elementwise_max(z[3], z[4]), z[5]);
                h2 m3 = __builtin_elementwise_max(__builtin_elementwise_max(z[6], z[7]), z[8]);
                h2 mm = __builtin_elementwise_max(__builtin_elementwise_max(m1, m2), m3);
                acc[it][r] = acc_dot2(mm, acc[it][r]);   // f32 accumulate
            }
        }
    }

    // ---- store: out[b, r, i, jg + it*2, f]; per (r,it) wave stores 256B
    const int jg = half * 32 + w * 8 + ps;
    #pragma unroll
    for (int r = 0; r < 4; ++r) {
        float* op = out + ((((b * 4 + r) * H_ + i) * W_ + jg) * F_ + f);
        #pragma unroll
        for (int it = 0; it < 4; ++it)
            op[it * 2 * F_] = acc[it][r];
    }
}

extern "C" void kernel_launch(void* const* d_in, const int* in_sizes, int n_in,
                              void* d_out, int out_size, void* d_ws, size_t ws_size,
                              hipStream_t stream) {
    const float* x    = (const float*)d_in[0];
    const float* kern = (const float*)d_in[1];
    const float* tker = (const float*)d_in[2];
    float* out = (float*)d_out;

    hipLaunchKernelGGL(mtp_main, dim3(B_ * H_ * 2), dim3(256), 0, stream,
                       x, kern, tker, out);
}